// Round 9
// baseline (76.290 us; speedup 1.0000x reference)
//
#include <hip/hip_runtime.h>
#include <hip/hip_bf16.h>

// Problem constants
#define HEIGHT 480
#define WIDTH  640
#define IN_CH  6
#define CIN    8      // p, 1-p, 6 features
#define COUT   32
#define BATCH  8
#define NPTS   16384
#define NPTOT  (BATCH * NPTS)          // 131072 = 2^17
// Padded grid: rows 0..482 (point rows 1..481), cols 0..642 (point cols 1..641)
#define GH 483
#define GW 643
#define NCELLS ((size_t)BATCH * GH * GW)   // 2,484,552 cells
#define NWORDS 77644                       // ceil(NCELLS/32)=77643, +1 guard word

// grid layout: [b][gy][gx][cin], cin contiguous (32B per cell, 32B-aligned)
__device__ __forceinline__ size_t cell_idx(int b, int gy, int gx) {
    return ((size_t)b * GH + gy) * GW + gx;
}

__device__ __forceinline__ void point_cell(const float4 q, int point,
                                           int& b, int& gy, int& gx) {
    gy = (int)rintf(q.z * (float)HEIGHT) + 1;   // padded coord
    gx = (int)rintf(q.y * (float)WIDTH) + 1;
    b  = point >> 14;                           // NPTS = 16384
}

// Phase 0: zero both bitmask arrays (2*NWORDS u32 = 621 KB, contiguous).
__global__ void zero_masks_kernel(uint4* __restrict__ m4, int n4) {
    int i = blockIdx.x * blockDim.x + threadIdx.x;
    if (i < n4) m4[i] = make_uint4(0u, 0u, 0u, 0u);
}

// Phase 1: per point, set occupancy bit; on collision (bit already set) also
// set the multi bit AND zero the grid cell (idempotent - all colliders write
// identical zeros; value writes happen only in the next dispatch).
__global__ void count_kernel(const float4* __restrict__ xytp,
                             unsigned int* __restrict__ occ,
                             unsigned int* __restrict__ multi,
                             float* __restrict__ grid) {
    int point = blockIdx.x * blockDim.x + threadIdx.x;
    if (point >= NPTOT) return;
    float4 q = xytp[point];
    int b, gy, gx;
    point_cell(q, point, b, gy, gx);
    size_t ci = cell_idx(b, gy, gx);
    unsigned int word = (unsigned int)(ci >> 5);
    unsigned int bit  = 1u << (ci & 31);
    unsigned int old = atomicOr(&occ[word], bit);
    if (old & bit) {                                  // rare (~3%)
        atomicOr(&multi[word], bit);
        float* cell = grid + (ci << 3);
        const float4 z = make_float4(0.f, 0.f, 0.f, 0.f);
        *(float4*)(cell)     = z;
        *(float4*)(cell + 4) = z;
    }
}

// Phase 2: multi bit clear (~97%) -> plain 32B store; else 8 f32 HW atomics
// into the cell count_kernel already zeroed.
__global__ void write_kernel(const float4* __restrict__ xytp,
                             const float*  __restrict__ feats,
                             const unsigned int* __restrict__ multi,
                             float* __restrict__ grid) {
    int point = blockIdx.x * blockDim.x + threadIdx.x;
    if (point >= NPTOT) return;
    float4 q = xytp[point];
    int b, gy, gx;
    point_cell(q, point, b, gy, gx);
    size_t ci = cell_idx(b, gy, gx);

    const float* f = feats + (size_t)point * IN_CH;
    float v0 = q.w, v1 = 1.0f - q.w;
    float f0 = f[0], f1 = f[1], f2 = f[2], f3 = f[3], f4 = f[4], f5 = f[5];

    unsigned int word = (unsigned int)(ci >> 5);
    unsigned int bit  = 1u << (ci & 31);

    float* cell = grid + (ci << 3);
    if (!(multi[word] & bit)) {
        *(float4*)(cell)     = make_float4(v0, v1, f0, f1);
        *(float4*)(cell + 4) = make_float4(f2, f3, f4, f5);
    } else {
        unsafeAtomicAdd(cell + 0, v0);
        unsafeAtomicAdd(cell + 1, v1);
        unsafeAtomicAdd(cell + 2, f0);
        unsafeAtomicAdd(cell + 3, f1);
        unsafeAtomicAdd(cell + 4, f2);
        unsafeAtomicAdd(cell + 5, f3);
        unsafeAtomicAdd(cell + 6, f4);
        unsafeAtomicAdd(cell + 7, f5);
    }
}

// Phase 3: 2 threads per point (half = tid>>17 is wave-uniform so W loads
// stay scalar). Branchless gather: all 9 cell loads issue up front; empty
// cells read the (always-occupied, cache-hot) center cell and are zeroed by
// multiply. Dense FMA block afterward - one latency exposure, no branches.
__global__ void __launch_bounds__(256)
conv_gather_kernel(const float4* __restrict__ xytp,
                   const float*  __restrict__ grid,
                   const unsigned int* __restrict__ occ,
                   const float*  __restrict__ W,     // [3][3][8][32]
                   const float*  __restrict__ bias,  // [32]
                   float* __restrict__ out) {
    int tid = blockIdx.x * blockDim.x + threadIdx.x;
    if (tid >= NPTOT * 2) return;
    int point = tid & (NPTOT - 1);
    int half  = tid >> 17;              // wave-uniform
    int cbase = half * 16;

    float4 q = xytp[point];
    int b, gy, gx;
    point_cell(q, point, b, gy, gx);
    size_t center  = cell_idx(b, gy, gx);
    size_t base_ci = center - GW - 1;   // padded window top-left

    // Gather 9 cells (two float4 each) with fallback-to-center addressing.
    float4 g0[9], g1[9];
    unsigned int occ9 = 0;
#pragma unroll
    for (int ky = 0; ky < 3; ++ky) {
        size_t ci_row = base_ci + (size_t)ky * GW;
        size_t word = ci_row >> 5;
        int sh = (int)(ci_row & 31);
        unsigned long long two =
            (((unsigned long long)occ[word + 1]) << 32) | occ[word];
        unsigned int bits = (unsigned int)(two >> sh) & 7u;
        occ9 |= bits << (ky * 3);
#pragma unroll
        for (int kx = 0; kx < 3; ++kx) {
            size_t ci = (bits & (1u << kx)) ? (ci_row + kx) : center;
            const float* cell = grid + (ci << 3);
            g0[ky * 3 + kx] = *(const float4*)(cell);
            g1[ky * 3 + kx] = *(const float4*)(cell + 4);
        }
    }

    float acc[16];
#pragma unroll
    for (int c = 0; c < 16; ++c) acc[c] = bias[cbase + c];

#pragma unroll
    for (int k = 0; k < 9; ++k) {
        float m = ((occ9 >> k) & 1u) ? 1.0f : 0.0f;
        float gv[CIN] = {g0[k].x * m, g0[k].y * m, g0[k].z * m, g0[k].w * m,
                         g1[k].x * m, g1[k].y * m, g1[k].z * m, g1[k].w * m};
        const float* wp = W + k * CIN * COUT + cbase;
#pragma unroll
        for (int ci2 = 0; ci2 < CIN; ++ci2) {
#pragma unroll
            for (int c = 0; c < 16; ++c) {
                acc[c] = fmaf(gv[ci2], wp[ci2 * COUT + c], acc[c]);
            }
        }
    }

    float* o = out + (size_t)point * COUT + cbase;
#pragma unroll
    for (int c = 0; c < 16; c += 4) {
        *(float4*)(o + c) = make_float4(acc[c], acc[c + 1], acc[c + 2], acc[c + 3]);
    }
}

extern "C" void kernel_launch(void* const* d_in, const int* in_sizes, int n_in,
                              void* d_out, int out_size, void* d_ws, size_t ws_size,
                              hipStream_t stream) {
    const float4* xytp  = (const float4*)d_in[0];   // (8,16384,4)
    const float*  feats = (const float*)d_in[1];    // (8,16384,6)
    const float*  W     = (const float*)d_in[2];    // (3,3,8,32)
    const float*  bias  = (const float*)d_in[3];    // (32,)
    float* out = (float*)d_out;                     // (8,16384,32)

    float* grid = (float*)d_ws;                     // 79.5 MB
    const size_t grid_bytes = NCELLS * CIN * sizeof(float);
    unsigned int* occ   = (unsigned int*)((char*)d_ws + grid_bytes);
    unsigned int* multi = occ + NWORDS;
    (void)ws_size;

    const int blk = 256;
    const int nblk_pts = (NPTOT + blk - 1) / blk;   // 512

    const int n4 = (2 * NWORDS) / 4;                // 38,822 uint4
    zero_masks_kernel<<<(n4 + blk - 1) / blk, blk, 0, stream>>>((uint4*)occ, n4);

    count_kernel<<<nblk_pts, blk, 0, stream>>>(xytp, occ, multi, grid);

    write_kernel<<<nblk_pts, blk, 0, stream>>>(xytp, feats, multi, grid);

    conv_gather_kernel<<<nblk_pts * 2, blk, 0, stream>>>(xytp, grid, occ, W, bias, out);
}

// Round 10
// 45.975 us; speedup vs baseline: 1.6594x; 1.6594x over previous
//
#include <hip/hip_runtime.h>
#include <hip/hip_bf16.h>

// Problem constants
#define HEIGHT 480
#define WIDTH  640
#define IN_CH  6
#define CIN    8      // p, 1-p, 6 features
#define COUT   32
#define BATCH  8
#define NPTS   16384
#define NPTOT  (BATCH * NPTS)          // 131072 = 2^17
// Padded grid: rows 0..482 (point rows 1..481), cols 0..642 (point cols 1..641)
#define GH 483
#define GW 643
#define NCELLS ((size_t)BATCH * GH * GW)   // 2,484,552 cells
#define NWORDS 77644                       // ceil(NCELLS/32)=77643, +1 guard word

// grid layout: [b][gy][gx][cin], cin contiguous (32B per cell, 32B-aligned)
__device__ __forceinline__ size_t cell_idx(int b, int gy, int gx) {
    return ((size_t)b * GH + gy) * GW + gx;
}

__device__ __forceinline__ void point_cell(const float4 q, int point,
                                           int& b, int& gy, int& gx) {
    gy = (int)rintf(q.z * (float)HEIGHT) + 1;   // padded coord
    gx = (int)rintf(q.y * (float)WIDTH) + 1;
    b  = point >> 14;                           // NPTS = 16384
}

// Phase 0: zero both bitmask arrays (2*NWORDS u32 = 621 KB, contiguous).
__global__ void zero_masks_kernel(uint4* __restrict__ m4, int n4) {
    int i = blockIdx.x * blockDim.x + threadIdx.x;
    if (i < n4) m4[i] = make_uint4(0u, 0u, 0u, 0u);
}

// Phase 1: per point, set occupancy bit; on collision (bit already set) also
// set the multi bit AND zero the grid cell (idempotent - all colliders write
// identical zeros; value writes happen only in the next dispatch).
__global__ void count_kernel(const float4* __restrict__ xytp,
                             unsigned int* __restrict__ occ,
                             unsigned int* __restrict__ multi,
                             float* __restrict__ grid) {
    int point = blockIdx.x * blockDim.x + threadIdx.x;
    if (point >= NPTOT) return;
    float4 q = xytp[point];
    int b, gy, gx;
    point_cell(q, point, b, gy, gx);
    size_t ci = cell_idx(b, gy, gx);
    unsigned int word = (unsigned int)(ci >> 5);
    unsigned int bit  = 1u << (ci & 31);
    unsigned int old = atomicOr(&occ[word], bit);
    if (old & bit) {                                  // rare (~3%)
        atomicOr(&multi[word], bit);
        float* cell = grid + (ci << 3);
        const float4 z = make_float4(0.f, 0.f, 0.f, 0.f);
        *(float4*)(cell)     = z;
        *(float4*)(cell + 4) = z;
    }
}

// Phase 2: multi bit clear (~97%) -> plain 32B store; else 8 f32 HW atomics
// into the cell count_kernel already zeroed.
__global__ void write_kernel(const float4* __restrict__ xytp,
                             const float*  __restrict__ feats,
                             const unsigned int* __restrict__ multi,
                             float* __restrict__ grid) {
    int point = blockIdx.x * blockDim.x + threadIdx.x;
    if (point >= NPTOT) return;
    float4 q = xytp[point];
    int b, gy, gx;
    point_cell(q, point, b, gy, gx);
    size_t ci = cell_idx(b, gy, gx);

    const float* f = feats + (size_t)point * IN_CH;
    float v0 = q.w, v1 = 1.0f - q.w;
    float f0 = f[0], f1 = f[1], f2 = f[2], f3 = f[3], f4 = f[4], f5 = f[5];

    unsigned int word = (unsigned int)(ci >> 5);
    unsigned int bit  = 1u << (ci & 31);

    float* cell = grid + (ci << 3);
    if (!(multi[word] & bit)) {
        *(float4*)(cell)     = make_float4(v0, v1, f0, f1);
        *(float4*)(cell + 4) = make_float4(f2, f3, f4, f5);
    } else {
        unsafeAtomicAdd(cell + 0, v0);
        unsafeAtomicAdd(cell + 1, v1);
        unsafeAtomicAdd(cell + 2, f0);
        unsafeAtomicAdd(cell + 3, f1);
        unsafeAtomicAdd(cell + 4, f2);
        unsafeAtomicAdd(cell + 5, f3);
        unsafeAtomicAdd(cell + 6, f4);
        unsafeAtomicAdd(cell + 7, f5);
    }
}

// Phase 3: 2 threads per point splitting the 9 window cells (even k -> sub 0
// incl. the always-occupied center, odd k -> sub 1). No load duplication,
// 2x waves for latency hiding. Masked loads issue in one batch (loads-only
// pass), then masked FMA pass; partials combined via __shfl_xor lane^1.
__global__ void __launch_bounds__(256)
conv_gather_kernel(const float4* __restrict__ xytp,
                   const float*  __restrict__ grid,
                   const unsigned int* __restrict__ occ,
                   const float*  __restrict__ W,     // [3][3][8][32]
                   const float*  __restrict__ bias,  // [32]
                   float* __restrict__ out) {
    int tid = blockIdx.x * blockDim.x + threadIdx.x;
    if (tid >= NPTOT * 2) return;
    int point = tid >> 1;
    int sub   = tid & 1;                // adjacent lanes share a point

    float4 q = xytp[point];
    int b, gy, gx;
    point_cell(q, point, b, gy, gx);
    size_t center  = cell_idx(b, gy, gx);
    size_t base_ci = center - GW - 1;   // padded window top-left

    // Occupancy bits for the 3x3 window (occ is 310KB -> L2-resident).
    unsigned int occ9 = 0;
#pragma unroll
    for (int ky = 0; ky < 3; ++ky) {
        size_t ci_row = base_ci + (size_t)ky * GW;
        size_t word = ci_row >> 5;
        int sh = (int)(ci_row & 31);
        unsigned long long two =
            (((unsigned long long)occ[word + 1]) << 32) | occ[word];
        occ9 |= ((unsigned int)(two >> sh) & 7u) << (ky * 3);
    }

    // My cells: k with (k&1)==sub. Loads-only masked pass (one latency window).
    float4 g0[5], g1[5];
#pragma unroll
    for (int k = 0; k < 9; ++k) {
        if ((k & 1) == sub) {
            if (occ9 & (1u << k)) {
                size_t ci = base_ci + (size_t)(k / 3) * GW + (k % 3);
                const float* cell = grid + (ci << 3);
                g0[k >> 1] = *(const float4*)(cell);
                g1[k >> 1] = *(const float4*)(cell + 4);
            }
        }
    }

    // Masked FMA pass over my cells.
    float acc[COUT];
#pragma unroll
    for (int c = 0; c < COUT; ++c) acc[c] = sub ? 0.0f : bias[c];

#pragma unroll
    for (int k = 0; k < 9; ++k) {
        if ((k & 1) == sub) {
            if (occ9 & (1u << k)) {
                float4 a = g0[k >> 1], d = g1[k >> 1];
                float gv[CIN] = {a.x, a.y, a.z, a.w, d.x, d.y, d.z, d.w};
                const float* wp = W + k * CIN * COUT;
#pragma unroll
                for (int ci2 = 0; ci2 < CIN; ++ci2) {
#pragma unroll
                    for (int c = 0; c < COUT; ++c) {
                        acc[c] = fmaf(gv[ci2], wp[ci2 * COUT + c], acc[c]);
                    }
                }
            }
        }
    }

    // Pair-reduce: I need partner's partial for MY 16 channels.
    // Compile-time register indices only (runtime-indexed arrays -> scratch).
    float res[16];
#pragma unroll
    for (int c = 0; c < 16; ++c) {
        float mine  = sub ? acc[16 + c] : acc[c];      // my half, my partial
        float other = sub ? acc[c]      : acc[16 + c]; // partner-half, my partial
        res[c] = mine + __shfl_xor(other, 1);
    }

    // Pairs write contiguous 128B: sub0 -> ch 0-15, sub1 -> ch 16-31.
    float* o = out + (size_t)point * COUT + sub * 16;
#pragma unroll
    for (int c = 0; c < 16; c += 4) {
        *(float4*)(o + c) = make_float4(res[c], res[c + 1], res[c + 2], res[c + 3]);
    }
}

extern "C" void kernel_launch(void* const* d_in, const int* in_sizes, int n_in,
                              void* d_out, int out_size, void* d_ws, size_t ws_size,
                              hipStream_t stream) {
    const float4* xytp  = (const float4*)d_in[0];   // (8,16384,4)
    const float*  feats = (const float*)d_in[1];    // (8,16384,6)
    const float*  W     = (const float*)d_in[2];    // (3,3,8,32)
    const float*  bias  = (const float*)d_in[3];    // (32,)
    float* out = (float*)d_out;                     // (8,16384,32)

    float* grid = (float*)d_ws;                     // 79.5 MB
    const size_t grid_bytes = NCELLS * CIN * sizeof(float);
    unsigned int* occ   = (unsigned int*)((char*)d_ws + grid_bytes);
    unsigned int* multi = occ + NWORDS;
    (void)ws_size;

    const int blk = 256;
    const int nblk_pts = (NPTOT + blk - 1) / blk;   // 512

    const int n4 = (2 * NWORDS) / 4;                // 38,822 uint4
    zero_masks_kernel<<<(n4 + blk - 1) / blk, blk, 0, stream>>>((uint4*)occ, n4);

    count_kernel<<<nblk_pts, blk, 0, stream>>>(xytp, occ, multi, grid);

    write_kernel<<<nblk_pts, blk, 0, stream>>>(xytp, feats, multi, grid);

    conv_gather_kernel<<<nblk_pts * 2, blk, 0, stream>>>(xytp, grid, occ, W, bias, out);
}